// Round 7
// baseline (91.249 us; speedup 1.0000x reference)
//
#include <hip/hip_runtime.h>
#include <hip/hip_bf16.h>
#include <stdint.h>

#define NROWS 8192
#define DIM 512

typedef short bf16x8 __attribute__((ext_vector_type(8)));
typedef float f32x4 __attribute__((ext_vector_type(4)));

__device__ __forceinline__ unsigned short f2bf(float f) {
    union { float f; uint32_t u; } c; c.f = f;
    uint32_t u = c.u;
    return (unsigned short)((u + 0x7FFFu + ((u >> 16) & 1u)) >> 16);
}

__device__ __forceinline__ void gload16(const unsigned short* g, unsigned short* l) {
    __builtin_amdgcn_global_load_lds((const __attribute__((address_space(1))) void*)g,
                                     (__attribute__((address_space(3))) void*)l,
                                     16, 0, 0);
}

// ---------------- Kernel 1: L2-normalize rows -> bf16; also zero pos/neg ----------------
__global__ __launch_bounds__(256) void knorm(const float* __restrict__ in,
                                             unsigned short* __restrict__ out,
                                             float* __restrict__ pos,
                                             float* __restrict__ neg) {
    const int row  = (blockIdx.x << 2) + (threadIdx.x >> 6);
    const int lane = threadIdx.x & 63;
    if (threadIdx.x < 4)      pos[(blockIdx.x << 2) + threadIdx.x] = 0.0f;
    else if (threadIdx.x < 8) neg[(blockIdx.x << 2) + threadIdx.x - 4] = 0.0f;

    const float4* src = (const float4*)(in + (size_t)row * DIM);
    float4 a = src[lane];
    float4 b = src[lane + 64];
    float ss = a.x*a.x + a.y*a.y + a.z*a.z + a.w*a.w
             + b.x*b.x + b.y*b.y + b.z*b.z + b.w*b.w;
    #pragma unroll
    for (int m = 1; m < 64; m <<= 1) ss += __shfl_xor(ss, m);
    const float inv = 1.0f / sqrtf(ss);
    ushort4* dst = (ushort4*)(out + (size_t)row * DIM);
    ushort4 o;
    o.x = f2bf(a.x*inv); o.y = f2bf(a.y*inv); o.z = f2bf(a.z*inv); o.w = f2bf(a.w*inv);
    dst[lane] = o;
    o.x = f2bf(b.x*inv); o.y = f2bf(b.y*inv); o.z = f2bf(b.z*inv); o.w = f2bf(b.w*inv);
    dst[lane + 64] = o;
}

// ---------------- Kernel 2: upper-triangle E*E^T + exp + mask + reduce ----------------
// 256x256 tile, 16 waves (4x4, each 64x64), BK=32, K=512 -> 16 K-steps.
// DEPTH-3 PREFETCH: 4 LDS buffers (128 KB); per K-step
//   barrier (buf (kt+3)%4 free) -> STAGE(kt+3) -> vmcnt(6) (kt's loads
//   landed, 6 stay in flight) -> barrier -> COMPUTE(kt).
// Load-landing cover = 3 COMPUTE phases + 6 barriers (~1000 cyc), vs R5's
// single-step cover (~300 cyc) that exposed latency every K-step.
// Supertile XCD map (R2/R5-verified, FETCH ~36 MB): triangle of 4x4
// supertiles of 8x8 blocks; 528 = 8 XCDs x 66 contiguous.
// Swizzle (rows 64 B = 4 16B-groups): stored group = g ^ ((r>>1)&3);
// linear LDS dest + inverse-swizzled global source + same-XOR ds_read
// (0 conflicts, verified R0-R5).
__global__ __launch_bounds__(1024, 1) void kgemm(const unsigned short* __restrict__ E,
                                                 float* __restrict__ pos,
                                                 float* __restrict__ neg) {
    __shared__ unsigned short lds[4][2][256 * 32];   // [buf][A/B][256 rows x 32]

    const int tid = threadIdx.x;
    const int w = tid >> 6;          // 0..15
    const int l = tid & 63;

    // ---- block id -> (bi, bj): supertile triangle decode ----
    int rem = (int)((blockIdx.x & 7) * 66 + (blockIdx.x >> 3));
    int SI = -1, SJ = -1;
    #pragma unroll
    for (int s = 0; s < 10; s++) {
        constexpr int si_t[10] = {0,0,0,0,1,1,1,2,2,3};
        constexpr int sj_t[10] = {0,1,2,3,1,2,3,2,3,3};
        const int sz = (si_t[s] == sj_t[s]) ? 36 : 64;
        if (SI < 0) {
            if (rem < sz) { SI = si_t[s]; SJ = sj_t[s]; }
            else rem -= sz;
        }
    }
    int bi, bj;
    if (SI == SJ) {
        int x = 0;
        while (rem >= 8 - x) { rem -= 8 - x; x++; }
        bi = (SI << 3) + x; bj = (SI << 3) + x + rem;
    } else {
        bi = (SI << 3) + (rem >> 3);
        bj = (SJ << 3) + (rem & 7);
    }

    const int brow = bi << 8;
    const int bcol = bj << 8;
    const int wr = (w >> 2) << 6;        // 0,64,128,192
    const int wc = (w & 3) << 6;         // 0,64,128,192

    f32x4 acc[4][4];
    #pragma unroll
    for (int i = 0; i < 4; i++)
        #pragma unroll
        for (int j = 0; j < 4; j++) acc[i][j] = (f32x4)0.0f;

    const int g_src = (l & 3) ^ ((l >> 3) & 3);
    const int r_st  = (w << 4) + (l >> 2);          // tile row 0..255

    auto STAGE = [&](int buf, int kt) {
        const size_t colb = (size_t)((kt << 5) + (g_src << 3));
        gload16(E + (size_t)(brow + r_st) * DIM + colb, &lds[buf][0][w << 9]);
        gload16(E + (size_t)(bcol + r_st) * DIM + colb, &lds[buf][1][w << 9]);
    };

    const int sgk = (((l >> 4) ^ ((l >> 1) & 3)) << 3);  // swizzled ushort offset

    auto COMPUTE = [&](int buf) {
        const unsigned short* sA = lds[buf][0];
        const unsigned short* sB = lds[buf][1];
        bf16x8 aF[4], bF[4];
        #pragma unroll
        for (int mi = 0; mi < 4; mi++) {
            const int rr = wr + (mi << 4) + (l & 15);
            aF[mi] = *(const bf16x8*)&sA[(rr << 5) + sgk];
        }
        #pragma unroll
        for (int ni = 0; ni < 4; ni++) {
            const int rr = wc + (ni << 4) + (l & 15);
            bF[ni] = *(const bf16x8*)&sB[(rr << 5) + sgk];
        }
        #pragma unroll
        for (int mi = 0; mi < 4; mi++)
            #pragma unroll
            for (int ni = 0; ni < 4; ni++)
                acc[mi][ni] = __builtin_amdgcn_mfma_f32_16x16x32_bf16(
                    aF[mi], bF[ni], acc[mi][ni], 0, 0, 0);
    };

    STAGE(0, 0);
    STAGE(1, 1);
    STAGE(2, 2);
    #pragma unroll
    for (int kt = 0; kt < 16; kt++) {
        if (kt > 0) __builtin_amdgcn_s_barrier();    // buf (kt+3)&3 free
        if (kt + 3 < 16) STAGE((kt + 3) & 3, kt + 3);
        // outstanding after stage: 2 loads per future step in flight
        if (kt <= 12)      asm volatile("s_waitcnt vmcnt(6)" ::: "memory");
        else if (kt == 13) asm volatile("s_waitcnt vmcnt(4)" ::: "memory");
        else if (kt == 14) asm volatile("s_waitcnt vmcnt(2)" ::: "memory");
        else               asm volatile("s_waitcnt vmcnt(0)" ::: "memory");
        __builtin_amdgcn_sched_barrier(0);
        __builtin_amdgcn_s_barrier();                // all waves: kt tile ready
        COMPUTE(kt & 3);
    }

    // ---- epilogue: exp(10*dot - 10), classify/scatter, reduce, atomics ----
    if (bi == bj) {
        #pragma unroll
        for (int mi = 0; mi < 4; mi++) {
            #pragma unroll
            for (int r = 0; r < 4; r++) {
                const int gi = brow + wr + (mi << 4) + ((l >> 4) << 2) + r;
                float p = 0.0f, n = 0.0f;
                #pragma unroll
                for (int ni = 0; ni < 4; ni++) {
                    const int gj = bcol + wc + (ni << 4) + (l & 15);
                    const float e = __expf(fmaf(acc[mi][ni][r], 10.0f, -10.0f));
                    if (gi == gj) {
                    } else if ((gi >> 2) == (gj >> 2)) {
                        p += e;
                    } else {
                        n += e;
                    }
                }
                #pragma unroll
                for (int m = 1; m < 16; m <<= 1) {
                    n += __shfl_xor(n, m);
                    p += __shfl_xor(p, m);
                }
                if ((l & 15) == 0) {
                    atomicAdd(&neg[gi], n);
                    atomicAdd(&pos[gi], p);
                }
            }
        }
    } else {
        float c[4] = {0.0f, 0.0f, 0.0f, 0.0f};
        #pragma unroll
        for (int mi = 0; mi < 4; mi++) {
            #pragma unroll
            for (int r = 0; r < 4; r++) {
                const int gi = brow + wr + (mi << 4) + ((l >> 4) << 2) + r;
                float n = 0.0f;
                #pragma unroll
                for (int ni = 0; ni < 4; ni++) {
                    const float e = __expf(fmaf(acc[mi][ni][r], 10.0f, -10.0f));
                    n += e;
                    c[ni] += e;
                }
                #pragma unroll
                for (int m = 1; m < 16; m <<= 1) n += __shfl_xor(n, m);
                if ((l & 15) == 0) atomicAdd(&neg[gi], n);
            }
        }
        #pragma unroll
        for (int ni = 0; ni < 4; ni++) {
            c[ni] += __shfl_xor(c[ni], 16);
            c[ni] += __shfl_xor(c[ni], 32);
            if ((l >> 4) == 0) {
                const int gj = bcol + wc + (ni << 4) + (l & 15);
                atomicAdd(&neg[gj], c[ni]);
            }
        }
    }
}

// ---------------- Kernel 3: final loss reduction ----------------
__global__ __launch_bounds__(1024) void kloss(const float* __restrict__ pos,
                                              const float* __restrict__ neg,
                                              float* __restrict__ out) {
    const int tid = threadIdx.x;
    float s = 0.0f;
    for (int i = tid; i < NROWS; i += 1024) {
        const float p = pos[i];
        const float n = neg[i];
        s += __logf(p + n + 1e-8f) - __logf(p);
    }
    #pragma unroll
    for (int m = 1; m < 64; m <<= 1) s += __shfl_xor(s, m);
    __shared__ float red[16];
    if ((tid & 63) == 0) red[tid >> 6] = s;
    __syncthreads();
    if (tid == 0) {
        float t = 0.0f;
        #pragma unroll
        for (int i = 0; i < 16; i++) t += red[i];
        out[0] = t / (float)NROWS;
    }
}

extern "C" void kernel_launch(void* const* d_in, const int* in_sizes, int n_in,
                              void* d_out, int out_size, void* d_ws, size_t ws_size,
                              hipStream_t stream) {
    (void)in_sizes; (void)n_in; (void)out_size; (void)ws_size;
    const float* emb = (const float*)d_in[0];
    unsigned short* En = (unsigned short*)d_ws;                       // 8 MB bf16
    float* pos = (float*)((char*)d_ws + (size_t)NROWS * DIM * 2);     // 32 KB
    float* neg = pos + NROWS;                                         // 32 KB

    knorm<<<NROWS / 4, 256, 0, stream>>>(emb, En, pos, neg);
    kgemm<<<528, 1024, 0, stream>>>(En, pos, neg);
    kloss<<<1, 1024, 0, stream>>>(pos, neg, (float*)d_out);
}